// Round 2
// baseline (11746.613 us; speedup 1.0000x reference)
//
#include <hip/hip_runtime.h>

typedef short short8 __attribute__((ext_vector_type(8)));
typedef float f32x4 __attribute__((ext_vector_type(4)));
typedef unsigned short u16;

#define NBLK 256
#define BDIM 512
#define BB 64
#define TT 512
#define II 512
#define HH 1024
#define NCLS 1000
#define HBUF (BB*HH)

__device__ __forceinline__ u16 f2bf(float f) {
  union { float f; unsigned u; } v; v.f = f;
  unsigned u = v.u;
  u += 0x7fffu + ((u >> 16) & 1u);   // RNE
  return (u16)(u >> 16);
}

__device__ __forceinline__ short8 cvt8(f32x4 a, f32x4 b) {
  short8 v;
  v[0] = (short)f2bf(a[0]); v[1] = (short)f2bf(a[1]);
  v[2] = (short)f2bf(a[2]); v[3] = (short)f2bf(a[3]);
  v[4] = (short)f2bf(b[0]); v[5] = (short)f2bf(b[1]);
  v[6] = (short)f2bf(b[2]); v[7] = (short)f2bf(b[3]);
  return v;
}

// Persistent fused 2-layer LSTM. 256 blocks: [0,128) = layer0, [128,256) = layer1.
// Stage s: layer0 computes t=s (s<=511), layer1 computes t=s-1 (s>=1). 513 stages,
// hierarchical grid barrier between stages. Each WG owns 8 hidden units (32 gate
// rows, i/f/g/o co-located), weights LDS-resident bf16 (XOR-swizzled), fp32
// c-state in registers. Inputs are FLOAT32; weights/x converted to bf16 for MFMA.
__global__ __launch_bounds__(BDIM, 2) void lstm2_fused(
    const float* __restrict__ x,
    const float* __restrict__ Wih0, const float* __restrict__ Whh0,
    const float* __restrict__ bih0, const float* __restrict__ bhh0,
    const float* __restrict__ Wih1, const float* __restrict__ Whh1,
    const float* __restrict__ bih1, const float* __restrict__ bhh1,
    u16* __restrict__ h0buf, u16* __restrict__ h1buf,
    float* __restrict__ h1f,
    unsigned* __restrict__ bar)
{
  __shared__ u16 wlds[32 * 2048];        // 128 KB (layer1 row = 2048 elems; layer0 uses 1536)
  __shared__ float gbuf[64][33];         // 8.4 KB gate staging (padded)
  __shared__ float blds[32];             // fused biases

  const bool isL1 = (blockIdx.x >= 128);
  const int wgl = isL1 ? (int)blockIdx.x - 128 : (int)blockIdx.x;
  const int j0 = wgl * 8;                // first hidden unit owned
  const int KX = isL1 ? HH : II;         // input-section K
  const int RL = KX + HH;                // total K per row: 2048 / 1536
  const int ROWB = RL * 2;               // row bytes in LDS (bf16)
  const float* Wih = isL1 ? Wih1 : Wih0;
  const float* Whh = isL1 ? Whh1 : Whh0;

  // ---- stage weights into LDS (f32 -> bf16), 16B granules, swizzle byte ^= (row&7)<<4 ----
  {
    const int cpr = RL / 8;              // 8-elem chunks per row
    for (int idx = threadIdx.x; idx < 32 * cpr; idx += BDIM) {
      int n = idx / cpr, cb = idx - n * cpr;
      int r = ((n >> 3) << 10) + j0 + (n & 7);   // global gate row: gate*1024 + j
      int k = cb * 8;
      const float* src = (k < KX) ? (Wih + (size_t)r * KX + k)
                                  : (Whh + (size_t)r * HH + (k - KX));
      f32x4 a = *(const f32x4*)src;
      f32x4 b = *(const f32x4*)(src + 4);
      short8 v = cvt8(a, b);
      unsigned byte = (unsigned)(n * ROWB + k * 2) ^ ((unsigned)(n & 7) << 4);
      *(short8*)((char*)wlds + byte) = v;
    }
    if (threadIdx.x < 32) {
      int n = threadIdx.x;
      int r = ((n >> 3) << 10) + j0 + (n & 7);
      blds[n] = (isL1 ? bih1[r] : bih0[r]) + (isL1 ? bhh1[r] : bhh0[r]);
    }
  }
  __syncthreads();

  const int lane = threadIdx.x & 63;
  const int wid = threadIdx.x >> 6;      // 8 waves
  const int mt = wid & 3, kg = wid >> 2; // 4 M-tiles x 2 K-halves
  const int m0 = mt << 4;
  const int row_a = m0 + (lane & 15);    // batch row for A fragments
  const int koff = (lane >> 4) << 3;     // k sub-offset per A/B layout
  const unsigned mask = (unsigned)(lane & 7) << 4;
  const unsigned nb0 = (unsigned)((lane & 15) * ROWB);
  const unsigned nb1 = nb0 + (unsigned)(16 * ROWB);
  const char* wch = (const char*)wlds;

  const int tb = threadIdx.x >> 3, tj = threadIdx.x & 7;  // update-phase (batch, unit)
  const int grp = blockIdx.x >> 5;       // 8 barrier groups of 32 blocks

  const int nsteps = RL >> 5;            // 48 / 64 k-steps of 32
  const int half = nsteps >> 1;
  const int ks_begin = kg * half, ks_end = ks_begin + half;
  const int bstep = KX >> 5;             // input-region / recurrent-region boundary
  const int r1e = (ks_end < bstep) ? ks_end : bstep;
  const int r2b = (ks_begin > bstep) ? ks_begin : bstep;

  float c_state = 0.f;

  for (int s = 0; s <= TT; ++s) {
    const bool active = isL1 ? (s >= 1) : (s < TT);
    if (active) {
      const int t = isL1 ? (s - 1) : s;
      f32x4 acc0 = {0.f, 0.f, 0.f, 0.f}, acc1 = {0.f, 0.f, 0.f, 0.f};

      // ---- input section ----
      if (!isL1) {
        const float* xr = x + (size_t)t * II + (size_t)row_a * ((size_t)TT * II);
#pragma unroll
        for (int ks = ks_begin; ks < r1e; ++ks) {
          int kk = (ks << 5) + koff;
          f32x4 fa = *(const f32x4*)(xr + kk);
          f32x4 fb = *(const f32x4*)(xr + kk + 4);
          short8 av = cvt8(fa, fb);
          unsigned o = (unsigned)(kk * 2) ^ mask;
          short8 bv0 = *(const short8*)(wch + (nb0 + o));
          short8 bv1 = *(const short8*)(wch + (nb1 + o));
          acc0 = __builtin_amdgcn_mfma_f32_16x16x32_bf16(av, bv0, acc0, 0, 0, 0);
          acc1 = __builtin_amdgcn_mfma_f32_16x16x32_bf16(av, bv1, acc1, 0, 0, 0);
        }
      } else {
        const u16* hr = h0buf + (size_t)((s + 1) & 1) * HBUF + (size_t)row_a * HH;
#pragma unroll
        for (int ks = ks_begin; ks < r1e; ++ks) {
          int kk = (ks << 5) + koff;
          short8 av = *(const short8*)(hr + kk);
          unsigned o = (unsigned)(kk * 2) ^ mask;
          short8 bv0 = *(const short8*)(wch + (nb0 + o));
          short8 bv1 = *(const short8*)(wch + (nb1 + o));
          acc0 = __builtin_amdgcn_mfma_f32_16x16x32_bf16(av, bv0, acc0, 0, 0, 0);
          acc1 = __builtin_amdgcn_mfma_f32_16x16x32_bf16(av, bv1, acc1, 0, 0, 0);
        }
      }
      // ---- recurrent section (own layer's h, bf16) ----
      {
        const u16* hp = (isL1 ? h1buf : h0buf) + (size_t)((s + 1) & 1) * HBUF
                        + (size_t)row_a * HH;
#pragma unroll
        for (int ks = r2b; ks < ks_end; ++ks) {
          int kk = (ks << 5) + koff;
          short8 av = *(const short8*)(hp + (kk - KX));
          unsigned o = (unsigned)(kk * 2) ^ mask;
          short8 bv0 = *(const short8*)(wch + (nb0 + o));
          short8 bv1 = *(const short8*)(wch + (nb1 + o));
          acc0 = __builtin_amdgcn_mfma_f32_16x16x32_bf16(av, bv0, acc0, 0, 0, 0);
          acc1 = __builtin_amdgcn_mfma_f32_16x16x32_bf16(av, bv1, acc1, 0, 0, 0);
        }
      }

      const int colA = lane & 15;
      const int rowD = m0 + ((lane >> 4) << 2);
      if (kg == 1) {
#pragma unroll
        for (int r = 0; r < 4; ++r) {
          gbuf[rowD + r][colA] = acc0[r];
          gbuf[rowD + r][colA + 16] = acc1[r];
        }
      }
      __syncthreads();
      if (kg == 0) {
#pragma unroll
        for (int r = 0; r < 4; ++r) {
          gbuf[rowD + r][colA] += acc0[r];
          gbuf[rowD + r][colA + 16] += acc1[r];
        }
      }
      __syncthreads();
      {   // ---- nonlinearity + state update: 512 threads = 64 batch x 8 units ----
        float gi = gbuf[tb][tj] + blds[tj];
        float gf = gbuf[tb][8 + tj] + blds[8 + tj];
        float gg = gbuf[tb][16 + tj] + blds[16 + tj];
        float go = gbuf[tb][24 + tj] + blds[24 + tj];
        gi = 1.f / (1.f + __expf(-gi));
        gf = 1.f / (1.f + __expf(-gf));
        go = 1.f / (1.f + __expf(-go));
        float e2 = __expf(2.f * fminf(15.f, fmaxf(-15.f, gg)));
        gg = (e2 - 1.f) / (e2 + 1.f);
        c_state = gf * c_state + gi * gg;
        float e2c = __expf(2.f * fminf(15.f, fmaxf(-15.f, c_state)));
        float th = (e2c - 1.f) / (e2c + 1.f);
        float hval = go * th;
        u16* hout = (isL1 ? h1buf : h0buf) + (size_t)(s & 1) * HBUF;
        hout[tb * HH + j0 + tj] = f2bf(hval);
        if (isL1) h1f[tb * HH + j0 + tj] = hval;   // f32 copy for dense head
      }
    }
    // ---- hierarchical grid barrier (monotone phases) ----
    if (s < TT) {
      __syncthreads();
      if (threadIdx.x == 0) {
        __threadfence();                               // release
        unsigned* gc = bar + 32 + grp * 32;
        unsigned old = atomicAdd(gc, 1u);
        if (old == (unsigned)(32 * (s + 1) - 1)) atomicAdd(bar, 1u);
        unsigned tgt = (unsigned)(8 * (s + 1));
        while (__hip_atomic_load(bar, __ATOMIC_RELAXED, __HIP_MEMORY_SCOPE_AGENT) < tgt)
          __builtin_amdgcn_s_sleep(4);
        __threadfence();                               // acquire
      }
      __syncthreads();
    }
  }
}

// out[b][c] = sum_k h1f[b][k] * Wd[c][k] + bd[c]   (all f32)
__global__ void dense_out(const float* __restrict__ h1, const float* __restrict__ Wd,
                          const float* __restrict__ bd, float* __restrict__ out)
{
  const int b  = threadIdx.x & 63;       // batch
  const int cl = threadIdx.x >> 6;
  const int cc = blockIdx.x * 4 + cl;    // class (250*4 = 1000)
  float acc = 0.f;
  const float* hrow = h1 + (size_t)b * HH;
  const float* wrow = Wd + (size_t)cc * HH;
#pragma unroll 8
  for (int k = 0; k < HH; k += 4) {
    f32x4 hv = *(const f32x4*)(hrow + k);
    f32x4 wv = *(const f32x4*)(wrow + k);
    acc += hv[0] * wv[0] + hv[1] * wv[1] + hv[2] * wv[2] + hv[3] * wv[3];
  }
  out[(size_t)b * NCLS + cc] = acc + bd[cc];
}

extern "C" void kernel_launch(void* const* d_in, const int* in_sizes, int n_in,
                              void* d_out, int out_size, void* d_ws, size_t ws_size,
                              hipStream_t stream)
{
  (void)in_sizes; (void)n_in; (void)out_size; (void)ws_size;
  const float* x    = (const float*)d_in[0];
  const float* Wih0 = (const float*)d_in[1];
  const float* Whh0 = (const float*)d_in[2];
  const float* bih0 = (const float*)d_in[3];
  const float* bhh0 = (const float*)d_in[4];
  const float* Wih1 = (const float*)d_in[5];
  const float* Whh1 = (const float*)d_in[6];
  const float* bih1 = (const float*)d_in[7];
  const float* bhh1 = (const float*)d_in[8];
  const float* Wd   = (const float*)d_in[9];
  const float* bd   = (const float*)d_in[10];

  unsigned* bar = (unsigned*)d_ws;                     // 2 KB barrier counters
  u16* h0buf = (u16*)((char*)d_ws + 2048);             // 2 x [64][1024] bf16
  u16* h1buf = h0buf + 2 * HBUF;
  float* h1f = (float*)((char*)d_ws + 2048 + (size_t)4 * HBUF * sizeof(u16));

  // zero barrier state + bf16 h double-buffers every launch (graph-replay deterministic)
  hipMemsetAsync(d_ws, 0, 2048 + (size_t)4 * HBUF * sizeof(u16), stream);

  hipLaunchKernelGGL(lstm2_fused, dim3(NBLK), dim3(BDIM), 0, stream,
                     x, Wih0, Whh0, bih0, bhh0, Wih1, Whh1, bih1, bhh1,
                     h0buf, h1buf, h1f, bar);
  hipLaunchKernelGGL(dense_out, dim3(250), dim3(256), 0, stream, h1f, Wd, bd,
                     (float*)d_out);
}

// Round 3
// 8677.971 us; speedup vs baseline: 1.3536x; 1.3536x over previous
//
#include <hip/hip_runtime.h>

typedef short short8 __attribute__((ext_vector_type(8)));
typedef float f32x4 __attribute__((ext_vector_type(4)));
typedef unsigned short u16;
typedef unsigned long long u64;

#define NBLK 256
#define BDIM 512
#define BB 64
#define TT 512
#define II 512
#define HH 1024
#define NCLS 1000
#define HBUF (BB*HH)

__device__ __forceinline__ u16 f2bf(float f) {
  union { float f; unsigned u; } v; v.f = f;
  unsigned u = v.u;
  u += 0x7fffu + ((u >> 16) & 1u);   // RNE
  return (u16)(u >> 16);
}

__device__ __forceinline__ short8 cvt8(f32x4 a, f32x4 b) {
  short8 v;
  v[0] = (short)f2bf(a[0]); v[1] = (short)f2bf(a[1]);
  v[2] = (short)f2bf(a[2]); v[3] = (short)f2bf(a[3]);
  v[4] = (short)f2bf(b[0]); v[5] = (short)f2bf(b[1]);
  v[6] = (short)f2bf(b[2]); v[7] = (short)f2bf(b[3]);
  return v;
}

// Device-coherent 16B load of h (bypasses non-coherent L1/L2, served at LLC).
__device__ __forceinline__ short8 load_h16(const u16* p) {
  u64 a = __hip_atomic_load((const u64*)p,     __ATOMIC_RELAXED, __HIP_MEMORY_SCOPE_AGENT);
  u64 b = __hip_atomic_load((const u64*)p + 1, __ATOMIC_RELAXED, __HIP_MEMORY_SCOPE_AGENT);
  union { u64 q[2]; short8 v; } u; u.q[0] = a; u.q[1] = b; return u.v;
}

// Persistent fused 2-layer LSTM. 256 blocks: [0,128) = layer0, [128,256) = layer1.
// Stage s: layer0 computes t=s (s<=511), layer1 computes t=s-1 (s>=1). 513 stages.
// Cross-block h exchange is fine-grained device-coherent (sc-flagged atomics);
// the grid barrier is relaxed atomics only — NO cache-sweeping threadfence.
__global__ __launch_bounds__(BDIM, 2) void lstm2_fused(
    const float* __restrict__ x,
    const float* __restrict__ Wih0, const float* __restrict__ Whh0,
    const float* __restrict__ bih0, const float* __restrict__ bhh0,
    const float* __restrict__ Wih1, const float* __restrict__ Whh1,
    const float* __restrict__ bih1, const float* __restrict__ bhh1,
    u16* __restrict__ h0buf, u16* __restrict__ h1buf,
    float* __restrict__ h1f,
    unsigned* __restrict__ bar)
{
  __shared__ u16 wlds[32 * 2048];        // 128 KB (layer1 row = 2048 elems; layer0 uses 1536)
  __shared__ float gbuf[64][33];         // 8.4 KB gate staging (padded)
  __shared__ float blds[32];             // fused biases

  const bool isL1 = (blockIdx.x >= 128);
  const int wgl = isL1 ? (int)blockIdx.x - 128 : (int)blockIdx.x;
  const int j0 = wgl * 8;                // first hidden unit owned
  const int KX = isL1 ? HH : II;         // input-section K
  const int RL = KX + HH;                // total K per row: 2048 / 1536
  const int ROWB = RL * 2;               // row bytes in LDS (bf16)
  const float* Wih = isL1 ? Wih1 : Wih0;
  const float* Whh = isL1 ? Whh1 : Whh0;

  // ---- stage weights into LDS (f32 -> bf16), 16B granules, swizzle byte ^= (row&7)<<4 ----
  {
    const int cpr = RL / 8;              // 8-elem chunks per row
    for (int idx = threadIdx.x; idx < 32 * cpr; idx += BDIM) {
      int n = idx / cpr, cb = idx - n * cpr;
      int r = ((n >> 3) << 10) + j0 + (n & 7);   // global gate row: gate*1024 + j
      int k = cb * 8;
      const float* src = (k < KX) ? (Wih + (size_t)r * KX + k)
                                  : (Whh + (size_t)r * HH + (k - KX));
      f32x4 a = *(const f32x4*)src;
      f32x4 b = *(const f32x4*)(src + 4);
      short8 v = cvt8(a, b);
      unsigned byte = (unsigned)(n * ROWB + k * 2) ^ ((unsigned)(n & 7) << 4);
      *(short8*)((char*)wlds + byte) = v;
    }
    if (threadIdx.x < 32) {
      int n = threadIdx.x;
      int r = ((n >> 3) << 10) + j0 + (n & 7);
      blds[n] = (isL1 ? bih1[r] : bih0[r]) + (isL1 ? bhh1[r] : bhh0[r]);
    }
  }
  __syncthreads();

  const int lane = threadIdx.x & 63;
  const int wid = threadIdx.x >> 6;      // 8 waves
  const int mt = wid & 3, kg = wid >> 2; // 4 M-tiles x 2 K-halves
  const int m0 = mt << 4;
  const int row_a = m0 + (lane & 15);    // batch row for A fragments
  const int koff = (lane >> 4) << 3;     // k sub-offset per A/B layout
  const unsigned mask = (unsigned)(lane & 7) << 4;
  const unsigned nb0 = (unsigned)((lane & 15) * ROWB);
  const unsigned nb1 = nb0 + (unsigned)(16 * ROWB);
  const char* wch = (const char*)wlds;

  const int tb = threadIdx.x >> 3, tj = threadIdx.x & 7;  // update-phase (batch, unit)
  const int grp = blockIdx.x >> 5;       // 8 barrier groups of 32 blocks

  const int nsteps = RL >> 5;            // 48 / 64 k-steps of 32
  const int half = nsteps >> 1;
  const int ks_begin = kg * half, ks_end = ks_begin + half;
  const int bstep = KX >> 5;             // input-region / recurrent-region boundary
  const int r1e = (ks_end < bstep) ? ks_end : bstep;
  const int r2b = (ks_begin > bstep) ? ks_begin : bstep;

  float c_state = 0.f;

  for (int s = 0; s <= TT; ++s) {
    const bool active = isL1 ? (s >= 1) : (s < TT);
    if (active) {
      const int t = isL1 ? (s - 1) : s;
      f32x4 acc0 = {0.f, 0.f, 0.f, 0.f}, acc1 = {0.f, 0.f, 0.f, 0.f};

      // ---- input section ----
      if (!isL1) {
        const float* xr = x + (size_t)t * II + (size_t)row_a * ((size_t)TT * II);
#pragma unroll
        for (int ks = ks_begin; ks < r1e; ++ks) {
          int kk = (ks << 5) + koff;
          f32x4 fa = *(const f32x4*)(xr + kk);
          f32x4 fb = *(const f32x4*)(xr + kk + 4);
          short8 av = cvt8(fa, fb);
          unsigned o = (unsigned)(kk * 2) ^ mask;
          short8 bv0 = *(const short8*)(wch + (nb0 + o));
          short8 bv1 = *(const short8*)(wch + (nb1 + o));
          acc0 = __builtin_amdgcn_mfma_f32_16x16x32_bf16(av, bv0, acc0, 0, 0, 0);
          acc1 = __builtin_amdgcn_mfma_f32_16x16x32_bf16(av, bv1, acc1, 0, 0, 0);
        }
      } else {
        const u16* hr = h0buf + (size_t)((s + 1) & 1) * HBUF + (size_t)row_a * HH;
#pragma unroll
        for (int ks = ks_begin; ks < r1e; ++ks) {
          int kk = (ks << 5) + koff;
          short8 av = load_h16(hr + kk);
          unsigned o = (unsigned)(kk * 2) ^ mask;
          short8 bv0 = *(const short8*)(wch + (nb0 + o));
          short8 bv1 = *(const short8*)(wch + (nb1 + o));
          acc0 = __builtin_amdgcn_mfma_f32_16x16x32_bf16(av, bv0, acc0, 0, 0, 0);
          acc1 = __builtin_amdgcn_mfma_f32_16x16x32_bf16(av, bv1, acc1, 0, 0, 0);
        }
      }
      // ---- recurrent section (own layer's h) ----
      {
        const u16* hp = (isL1 ? h1buf : h0buf) + (size_t)((s + 1) & 1) * HBUF
                        + (size_t)row_a * HH;
#pragma unroll
        for (int ks = r2b; ks < ks_end; ++ks) {
          int kk = (ks << 5) + koff;
          short8 av = load_h16(hp + (kk - KX));
          unsigned o = (unsigned)(kk * 2) ^ mask;
          short8 bv0 = *(const short8*)(wch + (nb0 + o));
          short8 bv1 = *(const short8*)(wch + (nb1 + o));
          acc0 = __builtin_amdgcn_mfma_f32_16x16x32_bf16(av, bv0, acc0, 0, 0, 0);
          acc1 = __builtin_amdgcn_mfma_f32_16x16x32_bf16(av, bv1, acc1, 0, 0, 0);
        }
      }

      const int colA = lane & 15;
      const int rowD = m0 + ((lane >> 4) << 2);
      if (kg == 1) {
#pragma unroll
        for (int r = 0; r < 4; ++r) {
          gbuf[rowD + r][colA] = acc0[r];
          gbuf[rowD + r][colA + 16] = acc1[r];
        }
      }
      __syncthreads();
      if (kg == 0) {
#pragma unroll
        for (int r = 0; r < 4; ++r) {
          gbuf[rowD + r][colA] += acc0[r];
          gbuf[rowD + r][colA + 16] += acc1[r];
        }
      }
      __syncthreads();
      {   // ---- nonlinearity + state update: 512 threads = 64 batch x 8 units ----
        float gi = gbuf[tb][tj] + blds[tj];
        float gf = gbuf[tb][8 + tj] + blds[8 + tj];
        float gg = gbuf[tb][16 + tj] + blds[16 + tj];
        float go = gbuf[tb][24 + tj] + blds[24 + tj];
        gi = 1.f / (1.f + __expf(-gi));
        gf = 1.f / (1.f + __expf(-gf));
        go = 1.f / (1.f + __expf(-go));
        float e2 = __expf(2.f * fminf(15.f, fmaxf(-15.f, gg)));
        gg = (e2 - 1.f) / (e2 + 1.f);
        c_state = gf * c_state + gi * gg;
        float e2c = __expf(2.f * fminf(15.f, fmaxf(-15.f, c_state)));
        float th = (e2c - 1.f) / (e2c + 1.f);
        float hval = go * th;

        // packed device-coherent bf16 store (pairs via shfl; even lanes store u32)
        unsigned hu = (unsigned)f2bf(hval);
        unsigned nbv = (unsigned)__shfl_xor((int)hu, 1);
        if ((tj & 1) == 0) {
          unsigned packed = hu | (nbv << 16);
          u16* hout = (isL1 ? h1buf : h0buf) + (size_t)(s & 1) * HBUF;
          unsigned* dst = (unsigned*)(hout + (size_t)tb * HH + j0 + tj);
          __hip_atomic_store(dst, packed, __ATOMIC_RELAXED, __HIP_MEMORY_SCOPE_AGENT);
        }
        if (isL1 && s == TT) h1f[(size_t)tb * HH + j0 + tj] = hval;  // f32 head input
      }
    }
    // ---- grid barrier: relaxed atomics only (h already device-coherent) ----
    if (s < TT) {
      __syncthreads();   // compiler drains vmcnt per-wave before s_barrier
      if (threadIdx.x == 0) {
        unsigned* gc = bar + 32 + grp * 32;
        unsigned old = atomicAdd(gc, 1u);
        if (old == (unsigned)(32 * (s + 1) - 1)) atomicAdd(bar, 1u);
        unsigned tgt = (unsigned)(8 * (s + 1));
        while (__hip_atomic_load(bar, __ATOMIC_RELAXED, __HIP_MEMORY_SCOPE_AGENT) < tgt)
          __builtin_amdgcn_s_sleep(2);
      }
      __syncthreads();
    }
  }
}

// out[b][c] = sum_k h1f[b][k] * Wd[c][k] + bd[c]   (all f32)
__global__ void dense_out(const float* __restrict__ h1, const float* __restrict__ Wd,
                          const float* __restrict__ bd, float* __restrict__ out)
{
  const int b  = threadIdx.x & 63;       // batch
  const int cl = threadIdx.x >> 6;
  const int cc = blockIdx.x * 4 + cl;    // class (250*4 = 1000)
  float acc = 0.f;
  const float* hrow = h1 + (size_t)b * HH;
  const float* wrow = Wd + (size_t)cc * HH;
#pragma unroll 8
  for (int k = 0; k < HH; k += 4) {
    f32x4 hv = *(const f32x4*)(hrow + k);
    f32x4 wv = *(const f32x4*)(wrow + k);
    acc += hv[0] * wv[0] + hv[1] * wv[1] + hv[2] * wv[2] + hv[3] * wv[3];
  }
  out[(size_t)b * NCLS + cc] = acc + bd[cc];
}

extern "C" void kernel_launch(void* const* d_in, const int* in_sizes, int n_in,
                              void* d_out, int out_size, void* d_ws, size_t ws_size,
                              hipStream_t stream)
{
  (void)in_sizes; (void)n_in; (void)out_size; (void)ws_size;
  const float* x    = (const float*)d_in[0];
  const float* Wih0 = (const float*)d_in[1];
  const float* Whh0 = (const float*)d_in[2];
  const float* bih0 = (const float*)d_in[3];
  const float* bhh0 = (const float*)d_in[4];
  const float* Wih1 = (const float*)d_in[5];
  const float* Whh1 = (const float*)d_in[6];
  const float* bih1 = (const float*)d_in[7];
  const float* bhh1 = (const float*)d_in[8];
  const float* Wd   = (const float*)d_in[9];
  const float* bd   = (const float*)d_in[10];

  unsigned* bar = (unsigned*)d_ws;                     // 2 KB barrier counters
  u16* h0buf = (u16*)((char*)d_ws + 2048);             // 2 x [64][1024] bf16
  u16* h1buf = h0buf + 2 * HBUF;
  float* h1f = (float*)((char*)d_ws + 2048 + (size_t)4 * HBUF * sizeof(u16));

  // zero barrier state + bf16 h double-buffers every launch (graph-replay deterministic)
  hipMemsetAsync(d_ws, 0, 2048 + (size_t)4 * HBUF * sizeof(u16), stream);

  hipLaunchKernelGGL(lstm2_fused, dim3(NBLK), dim3(BDIM), 0, stream,
                     x, Wih0, Whh0, bih0, bhh0, Wih1, Whh1, bih1, bhh1,
                     h0buf, h1buf, h1f, bar);
  hipLaunchKernelGGL(dense_out, dim3(250), dim3(256), 0, stream, h1f, Wd, bd,
                     (float*)d_out);
}